// Round 8
// baseline (438.878 us; speedup 1.0000x reference)
//
#include <hip/hip_runtime.h>
#include <hip/hip_bf16.h>

// MHA: B=2, S=4096, D=768, H=12, dk=64. fp32 in/out, bf16 MFMA internally.
// R8: W matrices pre-converted to bf16 (Wq/Wk/Wv stashed in d_out scratch, Wo in
// dead kp region); GEMMs upgraded to 128x128x64 tiles (4 waves, 4x4 acc each);
// flash: bf16 Wq staging + exp2 with log2e folded into Q scale.

typedef __attribute__((ext_vector_type(8))) short short8;
typedef __attribute__((ext_vector_type(4))) short short4v;
typedef __attribute__((ext_vector_type(4))) float floatx4;
typedef __attribute__((ext_vector_type(4))) float float4v;

#define S_LEN 4096
#define D_MODEL 768
#define NUM_HEADS 12
#define DK 64
#define BATCH 2
#define M_ROWS (BATCH * S_LEN)
#define HEADS_TOTAL (BATCH * NUM_HEADS)
#define P_STRIDE 76
#define QSCALE 0.18033688f   // 0.125 * log2(e): softmax via exp2 == exp

#if __has_builtin(__builtin_amdgcn_exp2f)
#define EXP2(x) __builtin_amdgcn_exp2f(x)
#else
#define EXP2(x) exp2f(x)
#endif

__device__ __forceinline__ unsigned short f2bf(float f) {
    union { float f; unsigned int i; } v; v.f = f;
    unsigned int r = v.i + 0x7fff + ((v.i >> 16) & 1);   // RNE
    return (unsigned short)(r >> 16);
}

__device__ __forceinline__ void stage8_f32(const float* __restrict__ src,
                                           unsigned short* __restrict__ dst) {
    float4v f0 = *(const float4v*)src;
    float4v f1 = *(const float4v*)(src + 4);
    unsigned short w[8];
#pragma unroll
    for (int j = 0; j < 4; ++j) { w[j] = f2bf(f0[j]); w[4 + j] = f2bf(f1[j]); }
    *(uint4*)dst = *(uint4*)w;
}

__device__ __forceinline__ short8 read8_p(const unsigned short* p) {
    short4v lo = *(const short4v*)p;
    short4v hi = *(const short4v*)(p + 4);
    short8 r;
    r[0]=lo[0]; r[1]=lo[1]; r[2]=lo[2]; r[3]=lo[3];
    r[4]=hi[0]; r[5]=hi[1]; r[6]=hi[2]; r[7]=hi[3];
    return r;
}

// fp32 -> bf16 elementwise (n multiple of 8).
__global__ __launch_bounds__(256) void convert_f32_bf16(
    const float* __restrict__ in, unsigned short* __restrict__ out, long n)
{
    long i = ((long)blockIdx.x * 256 + threadIdx.x) * 8;
    if (i + 8 > n) return;
    float4v a = *(const float4v*)(in + i);
    float4v b = *(const float4v*)(in + i + 4);
    unsigned short w[8];
#pragma unroll
    for (int j = 0; j < 4; ++j) { w[j] = f2bf(a[j]); w[4 + j] = f2bf(b[j]); }
    *(uint4*)(out + i) = *(uint4*)w;
}

// ---------------------------------------------------------------------------
// GEMM-BT 128x128x64: out[m,n] = sum_k X[m,k]*Wb[n,k] + bias[n].
// Wb bf16 (pre-converted), bias fp32. XF32: X fp32 (else bf16).
// MODE 0: fp32 row-major out. MODE 1: bf16 scatter [(b*H+h)*S+s][dk].
// MODE 2: bf16 V^T [(b*H+h)*DK+d][s] via swizzled LDS transpose.
// 256 threads / 4 waves; wave wv -> m-half (wv&1)*64, n-half (wv>>1)*64.
// ---------------------------------------------------------------------------
template <int MODE, int XF32>
__global__ __launch_bounds__(256) void gemm_bt(
    const void* __restrict__ Xv,
    const unsigned short* __restrict__ Wb,
    const float* __restrict__ bias,
    void* __restrict__ outv,
    int M, int N, int K)
{
    __shared__ __align__(16) unsigned short As[128][72];
    __shared__ __align__(16) unsigned short Bs[128][72];

    const int t    = threadIdx.x;
    const int wv   = t >> 6;
    const int lane = t & 63;
    const int l15  = lane & 15;
    const int quad = lane >> 4;
    const int m0   = blockIdx.x * 128;
    const int n0   = blockIdx.y * 128;
    const int mh   = (wv & 1) * 64;
    const int nh   = (wv >> 1) * 64;

    floatx4 acc[4][4];
#pragma unroll
    for (int i = 0; i < 4; ++i)
#pragma unroll
        for (int j = 0; j < 4; ++j) acc[i][j] = (floatx4){0.f, 0.f, 0.f, 0.f};

    const int sr = t >> 1;          // 0..127
    const int sc = (t & 1) * 32;    // 0 or 32

    for (int k0 = 0; k0 < K; k0 += 64) {
#pragma unroll
        for (int j = 0; j < 4; ++j) {
            if (XF32) {
                stage8_f32((const float*)Xv + (long)(m0 + sr) * K + k0 + sc + j * 8,
                           &As[sr][sc + j * 8]);
            } else {
                *(uint4*)(&As[sr][sc + j * 8]) =
                    *(const uint4*)((const unsigned short*)Xv + (long)(m0 + sr) * K + k0 + sc + j * 8);
            }
            *(uint4*)(&Bs[sr][sc + j * 8]) =
                *(const uint4*)(Wb + (long)(n0 + sr) * K + k0 + sc + j * 8);
        }
        __syncthreads();
#pragma unroll
        for (int kk = 0; kk < 2; ++kk) {
            short8 a4[4], b4[4];
#pragma unroll
            for (int mi = 0; mi < 4; ++mi)
                a4[mi] = *(const short8*)(&As[mh + mi * 16 + l15][kk * 32 + quad * 8]);
#pragma unroll
            for (int ni = 0; ni < 4; ++ni)
                b4[ni] = *(const short8*)(&Bs[nh + ni * 16 + l15][kk * 32 + quad * 8]);
#pragma unroll
            for (int mi = 0; mi < 4; ++mi)
#pragma unroll
                for (int ni = 0; ni < 4; ++ni)
                    acc[mi][ni] = __builtin_amdgcn_mfma_f32_16x16x32_bf16(
                        a4[mi], b4[ni], acc[mi][ni], 0, 0, 0);
        }
        __syncthreads();
    }

    if (MODE == 2) {
        // Stash C+bias (bf16) with col-swizzle; cols 0..63 -> As, 64..127 -> Bs.
        unsigned short (*BUFW)[72] = (wv >> 1) ? Bs : As;
#pragma unroll
        for (int ni = 0; ni < 4; ++ni) {
            const float bv = bias[n0 + nh + ni * 16 + l15];
#pragma unroll
            for (int mi = 0; mi < 4; ++mi)
#pragma unroll
                for (int reg = 0; reg < 4; ++reg) {
                    const int row = mh + mi * 16 + quad * 4 + reg;   // s-index in tile
                    const int col = ni * 16 + l15;                    // d-index
                    BUFW[row][col ^ (((row >> 3) & 7) << 3)] = f2bf(acc[mi][ni][reg] + bv);
                }
        }
        __syncthreads();
        const int bb = m0 >> 12;
        const int h0 = n0 >> 6;            // first head of this n-tile (covers h0, h0+1)
        const int schunk = t & 15;         // 8-s chunk
        const int sl = schunk * 8;
#pragma unroll
        for (int buf = 0; buf < 2; ++buf) {
            unsigned short (*BUFR)[72] = buf ? Bs : As;
#pragma unroll
            for (int p = 0; p < 4; ++p) {
                const int d = (t >> 4) * 4 + p;
                const int colp = d ^ ((schunk & 7) << 3);
                unsigned short w[8];
#pragma unroll
                for (int j = 0; j < 8; ++j) w[j] = BUFR[sl + j][colp];
                unsigned short* outp = (unsigned short*)outv +
                    ((long)((bb * NUM_HEADS + h0 + buf) * DK + d)) * S_LEN + (m0 & 4095) + sl;
                *(uint4*)outp = *(uint4*)w;
            }
        }
        return;
    }

#pragma unroll
    for (int ni = 0; ni < 4; ++ni) {
        const int col = n0 + nh + ni * 16 + l15;
        const float bv = bias[col];
#pragma unroll
        for (int mi = 0; mi < 4; ++mi)
#pragma unroll
            for (int reg = 0; reg < 4; ++reg) {
                const int row = m0 + mh + mi * 16 + quad * 4 + reg;
                const float o = acc[mi][ni][reg] + bv;
                if (MODE == 0) {
                    ((float*)outv)[(long)row * N + col] = o;
                } else {
                    const int bb = row >> 12;
                    const int ss = row & 4095;
                    const int h  = col >> 6;
                    const int d  = col & 63;
                    ((unsigned short*)outv)[(((long)bb * NUM_HEADS + h) * S_LEN + ss) * DK + d] = f2bf(o);
                }
            }
    }
}

// ---------------------------------------------------------------------------
// Flash attention (R7 structure): fused Q proj (bf16 Wq), no-rescale softmax
// via exp2 (log2e folded into Q scale), Q-frags in registers, 2 barriers/tile.
// ---------------------------------------------------------------------------
__global__ __launch_bounds__(256, 5) void flash_attn_fused(
    const float* __restrict__ Xq,
    const unsigned short* __restrict__ Wqb,   // [768,768] bf16
    const float* __restrict__ bq,
    const unsigned short* __restrict__ Kg,    // [bh][s][dk] bf16
    const unsigned short* __restrict__ VTg,   // [bh][d][s]  bf16
    unsigned short* __restrict__ ctx)         // [B,S,768]   bf16
{
    __shared__ __align__(16) unsigned short Ks[64][72];
    __shared__ __align__(16) unsigned short QVs[64][72];
    __shared__ __align__(16) unsigned short Pls[64][P_STRIDE];

    const int t    = threadIdx.x;
    const int wv   = t >> 6;
    const int lane = t & 63;
    const int l15  = lane & 15;
    const int quad = lane >> 4;
    const int q0   = blockIdx.x * 64;
    const int bh   = blockIdx.y;
    const int bb   = bh / NUM_HEADS;
    const int h    = bh % NUM_HEADS;
    const long kbase = (long)bh * S_LEN * DK;
    const long vbase = (long)bh * DK * S_LEN;

    const int srow = t >> 3;
    const int scol = (t & 7) * 8;

    // ---- Phase 0: Q-tile projection ----
    {
        floatx4 qacc[4];
#pragma unroll
        for (int i = 0; i < 4; ++i) qacc[i] = (floatx4){0.f, 0.f, 0.f, 0.f};

        for (int k0 = 0; k0 < D_MODEL; k0 += 64) {
#pragma unroll
            for (int p = 0; p < 2; ++p) {
                const int r = p * 32 + srow;
                stage8_f32(Xq + ((long)bb * S_LEN + q0 + r) * D_MODEL + k0 + scol, &Ks[r][scol]);
                *(uint4*)(&QVs[r][scol]) =
                    *(const uint4*)(Wqb + (long)(h * DK + r) * D_MODEL + k0 + scol);
            }
            __syncthreads();
#pragma unroll
            for (int kk = 0; kk < 2; ++kk) {
                short8 a = *(const short8*)(&Ks[wv * 16 + l15][kk * 32 + quad * 8]);
#pragma unroll
                for (int nj = 0; nj < 4; ++nj) {
                    short8 b = *(const short8*)(&QVs[nj * 16 + l15][kk * 32 + quad * 8]);
                    qacc[nj] = __builtin_amdgcn_mfma_f32_16x16x32_bf16(a, b, qacc[nj], 0, 0, 0);
                }
            }
            __syncthreads();
        }
#pragma unroll
        for (int nj = 0; nj < 4; ++nj) {
            const float bv = bq[h * DK + nj * 16 + l15];
#pragma unroll
            for (int reg = 0; reg < 4; ++reg) {
                const int row = wv * 16 + quad * 4 + reg;
                QVs[row][nj * 16 + l15] = f2bf((qacc[nj][reg] + bv) * QSCALE);
            }
        }
    }
    __syncthreads();

    short8 qfrag[2];
#pragma unroll
    for (int kk = 0; kk < 2; ++kk)
        qfrag[kk] = *(const short8*)(&QVs[wv * 16 + l15][kk * 32 + quad * 8]);
    __syncthreads();

    float l_acc[4] = {0.f, 0.f, 0.f, 0.f};
    floatx4 acc[4];
#pragma unroll
    for (int i = 0; i < 4; ++i) acc[i] = (floatx4){0.f, 0.f, 0.f, 0.f};

    // ---- Phase 1: flash loop ----
    for (int k0 = 0; k0 < S_LEN; k0 += 64) {
#pragma unroll
        for (int p = 0; p < 2; ++p) {
            const int r = p * 32 + srow;
            *(uint4*)(&Ks[r][scol])  = *(const uint4*)(Kg  + kbase + (long)(k0 + r) * DK + scol);
            *(uint4*)(&QVs[r][scol]) = *(const uint4*)(VTg + vbase + (long)r * S_LEN + k0 + scol);
        }
        __syncthreads();

        floatx4 sc[4];
#pragma unroll
        for (int i = 0; i < 4; ++i) sc[i] = (floatx4){0.f, 0.f, 0.f, 0.f};
#pragma unroll
        for (int kk = 0; kk < 2; ++kk) {
#pragma unroll
            for (int nj = 0; nj < 4; ++nj) {
                short8 b = *(const short8*)(&Ks[nj * 16 + l15][kk * 32 + quad * 8]);
                sc[nj] = __builtin_amdgcn_mfma_f32_16x16x32_bf16(qfrag[kk], b, sc[nj], 0, 0, 0);
            }
        }

#pragma unroll
        for (int nj = 0; nj < 4; ++nj)
#pragma unroll
            for (int reg = 0; reg < 4; ++reg) {
                const float e = EXP2(sc[nj][reg]);   // == exp(q.k/8): scale folded
                sc[nj][reg] = e;
                l_acc[reg] += e;
            }
#pragma unroll
        for (int nj = 0; nj < 4; ++nj)
#pragma unroll
            for (int reg = 0; reg < 4; ++reg)
                Pls[wv * 16 + quad * 4 + reg][nj * 16 + l15] = f2bf(sc[nj][reg]);

#pragma unroll
        for (int kk = 0; kk < 2; ++kk) {
            short8 a = read8_p(&Pls[wv * 16 + l15][kk * 32 + quad * 8]);
#pragma unroll
            for (int dj = 0; dj < 4; ++dj) {
                short8 b = *(const short8*)(&QVs[dj * 16 + l15][kk * 32 + quad * 8]);
                acc[dj] = __builtin_amdgcn_mfma_f32_16x16x32_bf16(a, b, acc[dj], 0, 0, 0);
            }
        }
        __syncthreads();
    }

    float l_row[4];
#pragma unroll
    for (int reg = 0; reg < 4; ++reg) {
        float l = l_acc[reg];
#pragma unroll
        for (int d = 1; d < 16; d <<= 1) l += __shfl_xor(l, d);
        l_row[reg] = l;
    }
#pragma unroll
    for (int dj = 0; dj < 4; ++dj) {
#pragma unroll
        for (int reg = 0; reg < 4; ++reg) {
            const int ss = q0 + wv * 16 + quad * 4 + reg;
            const float v = acc[dj][reg] / l_row[reg];
            ctx[((long)bb * S_LEN + ss) * D_MODEL + h * DK + dj * 16 + l15] = f2bf(v);
        }
    }
}

__global__ void fill_sentinel(float* out, long n, float val) {
    long i = (long)blockIdx.x * blockDim.x + threadIdx.x;
    if (i < n) out[i] = val;
}

// ---------------------------------------------------------------------------
extern "C" void kernel_launch(void* const* d_in, const int* in_sizes, int n_in,
                              void* d_out, int out_size, void* d_ws, size_t ws_size,
                              hipStream_t stream)
{
    const float* q_in = (const float*)d_in[0];
    const float* k_in = (const float*)d_in[1];
    const float* v_in = (const float*)d_in[2];
    const float* Wq = (const float*)d_in[3];
    const float* bq = (const float*)d_in[4];
    const float* Wk = (const float*)d_in[5];
    const float* bk = (const float*)d_in[6];
    const float* Wv = (const float*)d_in[7];
    const float* bv = (const float*)d_in[8];
    const float* Wo = (const float*)d_in[9];
    const float* bo = (const float*)d_in[10];

    const long NELEM = (long)M_ROWS * D_MODEL;          // 6291456
    const long WN    = (long)D_MODEL * D_MODEL;         // 589824
    const size_t needed = (size_t)(3 * NELEM) * sizeof(unsigned short);  // 37.7 MB

    if (ws_size < needed) {
        const long n = (long)out_size;
        fill_sentinel<<<(n + 255) / 256, 256, 0, stream>>>((float*)d_out, n,
                                                           (float)(ws_size >> 20));
        return;
    }

    unsigned short* ws  = (unsigned short*)d_ws;
    unsigned short* kp  = ws;                 // [bh][s][dk]
    unsigned short* vtp = ws + NELEM;         // [bh][d][s]
    unsigned short* ctx = ws + 2 * NELEM;     // [B,S,768]

    // d_out doubles as scratch for Wq/Wk/Wv bf16 until the final GEMM rewrites it.
    unsigned short* Wq_bf = (unsigned short*)d_out;
    unsigned short* Wk_bf = Wq_bf + WN;
    unsigned short* Wv_bf = Wq_bf + 2 * WN;
    unsigned short* Wo_bf = kp;               // kp is dead after flash

    const int cgrid = (int)(WN / 8 / 256);    // 288
    convert_f32_bf16<<<cgrid, 256, 0, stream>>>(Wq, Wq_bf, WN);
    convert_f32_bf16<<<cgrid, 256, 0, stream>>>(Wk, Wk_bf, WN);
    convert_f32_bf16<<<cgrid, 256, 0, stream>>>(Wv, Wv_bf, WN);

    dim3 ggrid(M_ROWS / 128, D_MODEL / 128);  // 64 x 6
    gemm_bt<1, 1><<<ggrid, 256, 0, stream>>>(k_in, Wk_bf, bk, kp, M_ROWS, D_MODEL, D_MODEL);
    gemm_bt<2, 1><<<ggrid, 256, 0, stream>>>(v_in, Wv_bf, bv, vtp, M_ROWS, D_MODEL, D_MODEL);

    dim3 agrid(S_LEN / 64, HEADS_TOTAL);      // 64 x 24
    flash_attn_fused<<<agrid, 256, 0, stream>>>(q_in, Wq_bf, bq, kp, vtp, ctx);

    convert_f32_bf16<<<cgrid, 256, 0, stream>>>(Wo, Wo_bf, WN);
    gemm_bt<0, 0><<<ggrid, 256, 0, stream>>>(ctx, Wo_bf, bo, d_out, M_ROWS, D_MODEL, D_MODEL);
}